// Round 1
// baseline (3457.690 us; speedup 1.0000x reference)
//
#include <hip/hip_runtime.h>

#define N_NODESC 50000
#define N_EDGESC 600000
#define DIM 128
#define N_LAYERS 4
#define N_GRAPHS 128
#define BN_EPSF 1e-5f

// ---------------- CSR build ----------------

__global__ void hist_kernel(const int* __restrict__ dst, int* __restrict__ deg) {
    int e = blockIdx.x * blockDim.x + threadIdx.x;
    if (e < N_EDGESC) atomicAdd(&deg[dst[e]], 1);
}

__global__ void scan_kernel(const int* __restrict__ deg, int* __restrict__ offs) {
    __shared__ int sdata[1024];
    __shared__ int s_carry;
    const int t = threadIdx.x;
    if (t == 0) s_carry = 0;
    __syncthreads();
    for (int base = 0; base < N_NODESC; base += 1024) {
        int i = base + t;
        int v = (i < N_NODESC) ? deg[i] : 0;
        sdata[t] = v;
        __syncthreads();
        int x = v;
        for (int o = 1; o < 1024; o <<= 1) {
            int y = (t >= o) ? sdata[t - o] : 0;
            __syncthreads();
            x += y;
            sdata[t] = x;
            __syncthreads();
        }
        int carry = s_carry;
        if (i < N_NODESC) offs[i] = carry + x - v;   // exclusive
        int total = sdata[1023];
        __syncthreads();
        if (t == 0) s_carry = carry + total;
        __syncthreads();
    }
    if (t == 0) offs[N_NODESC] = s_carry;
}

__global__ void fill_kernel(const int* __restrict__ src, const int* __restrict__ dst,
                            int* __restrict__ cursor, int* __restrict__ csr) {
    int e = blockIdx.x * blockDim.x + threadIdx.x;
    if (e < N_EDGESC) {
        int p = atomicAdd(&cursor[dst[e]], 1);
        csr[p] = src[e];
    }
}

// ---------------- aggregation: agg[n] = h[n] + sum_{src->n} h[src] ----------------
// 32 threads per node (each owns 4 consecutive floats), 8 nodes per block.

__global__ __launch_bounds__(256) void agg_kernel(const float* __restrict__ h,
                                                  const int* __restrict__ offs,
                                                  const int* __restrict__ csr,
                                                  float* __restrict__ outp) {
    const int lane = threadIdx.x & 31;
    const int node = blockIdx.x * 8 + (threadIdx.x >> 5);
    const int c4 = lane << 2;
    float4 acc = *(const float4*)(h + (size_t)node * DIM + c4);
    const int e1 = offs[node + 1];
    for (int e = offs[node]; e < e1; ++e) {
        int s = csr[e];
        const float4 v = *(const float4*)(h + (size_t)s * DIM + c4);
        acc.x += v.x; acc.y += v.y; acc.z += v.z; acc.w += v.w;
    }
    *(float4*)(outp + (size_t)node * DIM + c4) = acc;
}

// ---------------- fused MLP: z = relu(in@W1+b1)@W2+b2, plus BN partial stats ----------------
// block = 256 threads, 64 nodes/block. Thread t: cols j4..j4+3 (j4 = (t&31)*4),
// nodes m0..m0+7 (m0 = (t>>5)*8). acc[8][4] in registers.

__global__ __launch_bounds__(256) void mlp_kernel(const float* __restrict__ in,
                                                  const float* __restrict__ W1,
                                                  const float* __restrict__ b1,
                                                  const float* __restrict__ W2,
                                                  const float* __restrict__ b2,
                                                  float* __restrict__ outp,
                                                  float* __restrict__ stats) {
    __shared__ float inT[64][132];   // row-major node rows, +4 pad
    __shared__ float wch[32][128];   // 32-row weight chunk
    const int t = threadIdx.x;
    const int j4 = (t & 31) << 2;
    const int m0 = (t >> 5) << 3;
    const int nodeBase = blockIdx.x * 64;

    // stage 64 input rows (zero-fill past end)
    for (int p = 0; p < 8; ++p) {
        int idx = p * 256 + t;            // float4 index, 2048 total
        int row = idx >> 5;
        int k4 = (idx & 31) << 2;
        int node = nodeBase + row;
        float4 v = make_float4(0.f, 0.f, 0.f, 0.f);
        if (node < N_NODESC) v = *(const float4*)(in + (size_t)node * DIM + k4);
        *(float4*)&inT[row][k4] = v;
    }

    float acc[8][4];
#pragma unroll
    for (int m = 0; m < 8; ++m)
#pragma unroll
        for (int jj = 0; jj < 4; ++jj) acc[m][jj] = 0.f;

    // ---- GEMM1: mid = in @ W1 ----
    for (int kc = 0; kc < 4; ++kc) {
        __syncthreads();                   // prev chunk consumed / inT staged
        for (int p = 0; p < 4; ++p) {
            int idx = p * 256 + t;         // 1024 float4
            int r = idx >> 5, c4 = (idx & 31) << 2;
            *(float4*)&wch[r][c4] = *(const float4*)(W1 + (size_t)(kc * 32 + r) * DIM + c4);
        }
        __syncthreads();
#pragma unroll
        for (int k = 0; k < 32; k += 4) {
            float4 w0 = *(float4*)&wch[k + 0][j4];
            float4 w1 = *(float4*)&wch[k + 1][j4];
            float4 w2v = *(float4*)&wch[k + 2][j4];
            float4 w3 = *(float4*)&wch[k + 3][j4];
#pragma unroll
            for (int m = 0; m < 8; ++m) {
                float4 iv = *(float4*)&inT[m0 + m][kc * 32 + k];
                acc[m][0] += iv.x * w0.x + iv.y * w1.x + iv.z * w2v.x + iv.w * w3.x;
                acc[m][1] += iv.x * w0.y + iv.y * w1.y + iv.z * w2v.y + iv.w * w3.y;
                acc[m][2] += iv.x * w0.z + iv.y * w1.z + iv.z * w2v.z + iv.w * w3.z;
                acc[m][3] += iv.x * w0.w + iv.y * w1.w + iv.z * w2v.w + iv.w * w3.w;
            }
        }
    }

    // bias + relu -> write mid back into inT
    {
        float4 bb = *(const float4*)(b1 + j4);
        __syncthreads();                   // all inT reads done
#pragma unroll
        for (int m = 0; m < 8; ++m) {
            float4 v;
            v.x = fmaxf(acc[m][0] + bb.x, 0.f);
            v.y = fmaxf(acc[m][1] + bb.y, 0.f);
            v.z = fmaxf(acc[m][2] + bb.z, 0.f);
            v.w = fmaxf(acc[m][3] + bb.w, 0.f);
            *(float4*)&inT[m0 + m][j4] = v;
            acc[m][0] = acc[m][1] = acc[m][2] = acc[m][3] = 0.f;
        }
    }

    // ---- GEMM2: z = mid @ W2 ----
    for (int kc = 0; kc < 4; ++kc) {
        __syncthreads();                   // mid writes done / prev chunk consumed
        for (int p = 0; p < 4; ++p) {
            int idx = p * 256 + t;
            int r = idx >> 5, c4 = (idx & 31) << 2;
            *(float4*)&wch[r][c4] = *(const float4*)(W2 + (size_t)(kc * 32 + r) * DIM + c4);
        }
        __syncthreads();
#pragma unroll
        for (int k = 0; k < 32; k += 4) {
            float4 w0 = *(float4*)&wch[k + 0][j4];
            float4 w1 = *(float4*)&wch[k + 1][j4];
            float4 w2v = *(float4*)&wch[k + 2][j4];
            float4 w3 = *(float4*)&wch[k + 3][j4];
#pragma unroll
            for (int m = 0; m < 8; ++m) {
                float4 iv = *(float4*)&inT[m0 + m][kc * 32 + k];
                acc[m][0] += iv.x * w0.x + iv.y * w1.x + iv.z * w2v.x + iv.w * w3.x;
                acc[m][1] += iv.x * w0.y + iv.y * w1.y + iv.z * w2v.y + iv.w * w3.y;
                acc[m][2] += iv.x * w0.z + iv.y * w1.z + iv.z * w2v.z + iv.w * w3.z;
                acc[m][3] += iv.x * w0.w + iv.y * w1.w + iv.z * w2v.w + iv.w * w3.w;
            }
        }
    }

    // bias, store z, accumulate BN partial sums
    float4 b2v = *(const float4*)(b2 + j4);
    float s1[4] = {0.f, 0.f, 0.f, 0.f};
    float s2[4] = {0.f, 0.f, 0.f, 0.f};
#pragma unroll
    for (int m = 0; m < 8; ++m) {
        int node = nodeBase + m0 + m;
        if (node < N_NODESC) {
            float4 z;
            z.x = acc[m][0] + b2v.x;
            z.y = acc[m][1] + b2v.y;
            z.z = acc[m][2] + b2v.z;
            z.w = acc[m][3] + b2v.w;
            *(float4*)(outp + (size_t)node * DIM + j4) = z;
            s1[0] += z.x; s2[0] += z.x * z.x;
            s1[1] += z.y; s2[1] += z.y * z.y;
            s1[2] += z.z; s2[2] += z.z * z.z;
            s1[3] += z.w; s2[3] += z.w * z.w;
        }
    }
    atomicAdd(&stats[j4 + 0], s1[0]);
    atomicAdd(&stats[j4 + 1], s1[1]);
    atomicAdd(&stats[j4 + 2], s1[2]);
    atomicAdd(&stats[j4 + 3], s1[3]);
    atomicAdd(&stats[DIM + j4 + 0], s2[0]);
    atomicAdd(&stats[DIM + j4 + 1], s2[1]);
    atomicAdd(&stats[DIM + j4 + 2], s2[2]);
    atomicAdd(&stats[DIM + j4 + 3], s2[3]);
}

// ---------------- BN finalize + apply ----------------

__global__ void bn_finalize(const float* __restrict__ stats, const float* __restrict__ gamma,
                            const float* __restrict__ beta, float* __restrict__ ab) {
    int j = threadIdx.x;
    float s1 = stats[j], s2 = stats[DIM + j];
    const float invN = 1.0f / (float)N_NODESC;
    float mean = s1 * invN;
    float var = s2 * invN - mean * mean;
    float a = gamma[j] * rsqrtf(var + BN_EPSF);
    float b = beta[j] - mean * a;
    ab[j] = a;
    ab[DIM + j] = b;
}

__global__ __launch_bounds__(256) void bn_apply(float* __restrict__ z, const float* __restrict__ ab) {
    int idx = blockIdx.x * blockDim.x + threadIdx.x;   // float4 index
    if (idx >= N_NODESC * DIM / 4) return;
    int j4 = (idx & 31) << 2;
    float4 a4 = *(const float4*)(ab + j4);
    float4 b4 = *(const float4*)(ab + DIM + j4);
    float4 v = *(float4*)(z + (size_t)idx * 4);
    v.x = fmaxf(v.x * a4.x + b4.x, 0.f);
    v.y = fmaxf(v.y * a4.y + b4.y, 0.f);
    v.z = fmaxf(v.z * a4.z + b4.z, 0.f);
    v.w = fmaxf(v.w * a4.w + b4.w, 0.f);
    *(float4*)(z + (size_t)idx * 4) = v;
}

// ---------------- global mean pool ----------------

__global__ __launch_bounds__(256) void pool_kernel(const float* __restrict__ h,
                                                   const int* __restrict__ batch,
                                                   float* __restrict__ outsum,
                                                   float* __restrict__ counts) {
    const int lane = threadIdx.x & 31;
    const int node = blockIdx.x * 8 + (threadIdx.x >> 5);
    const int c4 = lane << 2;
    int g = batch[node];
    const float4 v = *(const float4*)(h + (size_t)node * DIM + c4);
    atomicAdd(&outsum[g * DIM + c4 + 0], v.x);
    atomicAdd(&outsum[g * DIM + c4 + 1], v.y);
    atomicAdd(&outsum[g * DIM + c4 + 2], v.z);
    atomicAdd(&outsum[g * DIM + c4 + 3], v.w);
    if (lane == 0) atomicAdd(&counts[g], 1.0f);
}

__global__ void div_kernel(float* __restrict__ outsum, const float* __restrict__ counts) {
    int idx = blockIdx.x * blockDim.x + threadIdx.x;
    if (idx < N_GRAPHS * DIM) {
        float c = counts[idx >> 7];
        outsum[idx] = outsum[idx] / fmaxf(c, 1.0f);
    }
}

// ---------------- launcher ----------------

extern "C" void kernel_launch(void* const* d_in, const int* in_sizes, int n_in,
                              void* d_out, int out_size, void* d_ws, size_t ws_size,
                              hipStream_t stream) {
    const float* x     = (const float*)d_in[0];
    const int*   ei    = (const int*)d_in[1];
    const int*   batch = (const int*)d_in[2];
    const float* W1    = (const float*)d_in[3];
    const float* b1    = (const float*)d_in[4];
    const float* W2    = (const float*)d_in[5];
    const float* b2    = (const float*)d_in[6];
    const float* gamma = (const float*)d_in[7];
    const float* beta  = (const float*)d_in[8];
    float* out = (float*)d_out;

    char* ws = (char*)d_ws;
    size_t off = 0;
    auto alloc = [&](size_t bytes) -> void* {
        void* p = ws + off;
        off += (bytes + 255) & ~(size_t)255;
        return p;
    };
    int*   deg    = (int*)alloc((size_t)N_NODESC * 4);
    int*   offs   = (int*)alloc((size_t)(N_NODESC + 1) * 4);
    int*   cursor = (int*)alloc((size_t)N_NODESC * 4);
    int*   csr    = (int*)alloc((size_t)N_EDGESC * 4);
    float* stats  = (float*)alloc(256 * 4);
    float* ab     = (float*)alloc(256 * 4);
    float* counts = (float*)alloc(N_GRAPHS * 4);
    float* bufA   = (float*)alloc((size_t)N_NODESC * DIM * 4);
    float* bufZ   = (float*)alloc((size_t)N_NODESC * DIM * 4);

    const int* srcp = ei;
    const int* dstp = ei + N_EDGESC;

    // CSR build (once per launch; identical work every call)
    hipMemsetAsync(deg, 0, (size_t)N_NODESC * 4, stream);
    hist_kernel<<<(N_EDGESC + 255) / 256, 256, 0, stream>>>(dstp, deg);
    scan_kernel<<<1, 1024, 0, stream>>>(deg, offs);
    hipMemcpyAsync(cursor, offs, (size_t)N_NODESC * 4, hipMemcpyDeviceToDevice, stream);
    fill_kernel<<<(N_EDGESC + 255) / 256, 256, 0, stream>>>(srcp, dstp, cursor, csr);

    const float* hin = x;
    for (int l = 0; l < N_LAYERS; ++l) {
        hipMemsetAsync(stats, 0, 256 * 4, stream);
        agg_kernel<<<N_NODESC / 8, 256, 0, stream>>>(hin, offs, csr, bufA);
        mlp_kernel<<<(N_NODESC + 63) / 64, 256, 0, stream>>>(
            bufA, W1 + (size_t)l * DIM * DIM, b1 + (size_t)l * DIM,
            W2 + (size_t)l * DIM * DIM, b2 + (size_t)l * DIM, bufZ, stats);
        bn_finalize<<<1, DIM, 0, stream>>>(stats, gamma + (size_t)l * DIM, beta + (size_t)l * DIM, ab);
        bn_apply<<<N_NODESC * DIM / 4 / 256, 256, 0, stream>>>(bufZ, ab);
        hin = bufZ;
    }

    hipMemsetAsync(out, 0, (size_t)N_GRAPHS * DIM * 4, stream);
    hipMemsetAsync(counts, 0, (size_t)N_GRAPHS * 4, stream);
    pool_kernel<<<N_NODESC / 8, 256, 0, stream>>>(bufZ, batch, out, counts);
    div_kernel<<<(N_GRAPHS * DIM + 255) / 256, 256, 0, stream>>>(out, counts);
}

// Round 2
// 3111.414 us; speedup vs baseline: 1.1113x; 1.1113x over previous
//
#include <hip/hip_runtime.h>

#define N_NODESC 50000
#define N_EDGESC 600000
#define DIM 128
#define N_LAYERS 4
#define N_GRAPHS 128
#define BN_EPSF 1e-5f
#define NBLK 782          // ceil(N_NODESC / 64)
#define RED_ROWS 25       // ceil(NBLK / 32)

// ---------------- CSR build ----------------

__global__ void hist_kernel(const int* __restrict__ dst, int* __restrict__ deg) {
    int e = blockIdx.x * blockDim.x + threadIdx.x;
    if (e < N_EDGESC) atomicAdd(&deg[dst[e]], 1);
}

__global__ void scan_kernel(const int* __restrict__ deg, int* __restrict__ offs) {
    __shared__ int sdata[1024];
    __shared__ int s_carry;
    const int t = threadIdx.x;
    if (t == 0) s_carry = 0;
    __syncthreads();
    for (int base = 0; base < N_NODESC; base += 1024) {
        int i = base + t;
        int v = (i < N_NODESC) ? deg[i] : 0;
        sdata[t] = v;
        __syncthreads();
        int x = v;
        for (int o = 1; o < 1024; o <<= 1) {
            int y = (t >= o) ? sdata[t - o] : 0;
            __syncthreads();
            x += y;
            sdata[t] = x;
            __syncthreads();
        }
        int carry = s_carry;
        if (i < N_NODESC) offs[i] = carry + x - v;   // exclusive
        int total = sdata[1023];
        __syncthreads();
        if (t == 0) s_carry = carry + total;
        __syncthreads();
    }
    if (t == 0) offs[N_NODESC] = s_carry;
}

__global__ void fill_kernel(const int* __restrict__ src, const int* __restrict__ dst,
                            int* __restrict__ cursor, int* __restrict__ csr) {
    int e = blockIdx.x * blockDim.x + threadIdx.x;
    if (e < N_EDGESC) {
        int p = atomicAdd(&cursor[dst[e]], 1);
        csr[p] = src[e];
    }
}

// ---------------- graph boundaries (batch is sorted) ----------------

__global__ void ginit_kernel(int* __restrict__ gstart) {
    int i = threadIdx.x;
    if (i <= N_GRAPHS) gstart[i] = N_NODESC;
}

__global__ void gbound_kernel(const int* __restrict__ batch, int* __restrict__ gstart) {
    int i = blockIdx.x * blockDim.x + threadIdx.x;
    if (i >= N_NODESC) return;
    int b = batch[i];
    int bp = (i == 0) ? -1 : batch[i - 1];
    for (int g = bp + 1; g <= b; ++g) gstart[g] = i;
}

// ---------------- helpers ----------------

__device__ __forceinline__ float4 bnrelu4(float4 v, float4 a, float4 b) {
    float4 r;
    r.x = fmaxf(fmaf(v.x, a.x, b.x), 0.f);
    r.y = fmaxf(fmaf(v.y, a.y, b.y), 0.f);
    r.z = fmaxf(fmaf(v.z, a.z, b.z), 0.f);
    r.w = fmaxf(fmaf(v.w, a.w, b.w), 0.f);
    return r;
}

// ---------------- fused layer: gather(+BN/ReLU of prev layer) -> MLP -> z + BN partials ----------------
// block = 256 threads, 64 nodes/block.
// Gather: lane = t&31 owns cols lane*4..lane*4+3; group = t>>5 owns nodes grp, grp+8, ...
// GEMM:   j4 = (t&31)*4 cols, m0 = (t>>5)*8 node rows, acc[8][4] registers.

template <int APPLY>
__global__ __launch_bounds__(256, 3) void mlp_fused(const float* __restrict__ hin,
                                                    const float* __restrict__ ab,
                                                    const int* __restrict__ offs,
                                                    const int* __restrict__ csr,
                                                    const float* __restrict__ W1,
                                                    const float* __restrict__ b1,
                                                    const float* __restrict__ W2,
                                                    const float* __restrict__ b2,
                                                    float* __restrict__ zout,
                                                    float* __restrict__ partials) {
    __shared__ float inT[64][DIM];
    __shared__ float wch[32][DIM];
    const int t = threadIdx.x;
    const int lane = t & 31;
    const int grp = t >> 5;
    const int c4 = lane << 2;
    const int nodeBase = blockIdx.x * 64;

    float4 a4 = make_float4(1.f, 1.f, 1.f, 1.f);
    float4 bb4 = make_float4(0.f, 0.f, 0.f, 0.f);
    if (APPLY) {
        a4 = *(const float4*)(ab + c4);
        bb4 = *(const float4*)(ab + DIM + c4);
    }

    // ---- Phase A: gather neighbors + self, applying prev-layer BN+ReLU on the fly ----
    for (int m = grp; m < 64; m += 8) {
        int node = nodeBase + m;
        float4 acc = make_float4(0.f, 0.f, 0.f, 0.f);
        if (node < N_NODESC) {
            float4 v = *(const float4*)(hin + (size_t)node * DIM + c4);
            acc = APPLY ? bnrelu4(v, a4, bb4) : v;
            const int e1 = offs[node + 1];
            for (int e = offs[node]; e < e1; ++e) {
                int s = csr[e];
                float4 w = *(const float4*)(hin + (size_t)s * DIM + c4);
                if (APPLY) w = bnrelu4(w, a4, bb4);
                acc.x += w.x; acc.y += w.y; acc.z += w.z; acc.w += w.w;
            }
        }
        *(float4*)&inT[m][c4] = acc;
    }

    const int j4 = c4;
    const int m0 = grp << 3;
    float acc[8][4];
#pragma unroll
    for (int m = 0; m < 8; ++m)
#pragma unroll
        for (int jj = 0; jj < 4; ++jj) acc[m][jj] = 0.f;

    // ---- GEMM1: mid = in @ W1 ----
    for (int kc = 0; kc < 4; ++kc) {
        __syncthreads();
        for (int p = 0; p < 4; ++p) {
            int idx = p * 256 + t;
            int r = idx >> 5, cc = (idx & 31) << 2;
            *(float4*)&wch[r][cc] = *(const float4*)(W1 + (size_t)(kc * 32 + r) * DIM + cc);
        }
        __syncthreads();
#pragma unroll
        for (int k = 0; k < 32; k += 4) {
            float4 w0 = *(float4*)&wch[k + 0][j4];
            float4 w1 = *(float4*)&wch[k + 1][j4];
            float4 w2v = *(float4*)&wch[k + 2][j4];
            float4 w3 = *(float4*)&wch[k + 3][j4];
#pragma unroll
            for (int m = 0; m < 8; ++m) {
                float4 iv = *(float4*)&inT[m0 + m][kc * 32 + k];
                acc[m][0] += iv.x * w0.x + iv.y * w1.x + iv.z * w2v.x + iv.w * w3.x;
                acc[m][1] += iv.x * w0.y + iv.y * w1.y + iv.z * w2v.y + iv.w * w3.y;
                acc[m][2] += iv.x * w0.z + iv.y * w1.z + iv.z * w2v.z + iv.w * w3.z;
                acc[m][3] += iv.x * w0.w + iv.y * w1.w + iv.z * w2v.w + iv.w * w3.w;
            }
        }
    }

    // bias + relu -> write mid back into inT
    {
        float4 bb = *(const float4*)(b1 + j4);
        __syncthreads();
#pragma unroll
        for (int m = 0; m < 8; ++m) {
            float4 v;
            v.x = fmaxf(acc[m][0] + bb.x, 0.f);
            v.y = fmaxf(acc[m][1] + bb.y, 0.f);
            v.z = fmaxf(acc[m][2] + bb.z, 0.f);
            v.w = fmaxf(acc[m][3] + bb.w, 0.f);
            *(float4*)&inT[m0 + m][j4] = v;
            acc[m][0] = acc[m][1] = acc[m][2] = acc[m][3] = 0.f;
        }
    }

    // ---- GEMM2: z = mid @ W2 ----
    for (int kc = 0; kc < 4; ++kc) {
        __syncthreads();
        for (int p = 0; p < 4; ++p) {
            int idx = p * 256 + t;
            int r = idx >> 5, cc = (idx & 31) << 2;
            *(float4*)&wch[r][cc] = *(const float4*)(W2 + (size_t)(kc * 32 + r) * DIM + cc);
        }
        __syncthreads();
#pragma unroll
        for (int k = 0; k < 32; k += 4) {
            float4 w0 = *(float4*)&wch[k + 0][j4];
            float4 w1 = *(float4*)&wch[k + 1][j4];
            float4 w2v = *(float4*)&wch[k + 2][j4];
            float4 w3 = *(float4*)&wch[k + 3][j4];
#pragma unroll
            for (int m = 0; m < 8; ++m) {
                float4 iv = *(float4*)&inT[m0 + m][kc * 32 + k];
                acc[m][0] += iv.x * w0.x + iv.y * w1.x + iv.z * w2v.x + iv.w * w3.x;
                acc[m][1] += iv.x * w0.y + iv.y * w1.y + iv.z * w2v.y + iv.w * w3.y;
                acc[m][2] += iv.x * w0.z + iv.y * w1.z + iv.z * w2v.z + iv.w * w3.z;
                acc[m][3] += iv.x * w0.w + iv.y * w1.w + iv.z * w2v.w + iv.w * w3.w;
            }
        }
    }

    // ---- Phase C: bias, store z, block-reduce BN partial sums (NO global atomics) ----
    float4 b2v = *(const float4*)(b2 + j4);
    float s1[4] = {0.f, 0.f, 0.f, 0.f};
    float s2[4] = {0.f, 0.f, 0.f, 0.f};
#pragma unroll
    for (int m = 0; m < 8; ++m) {
        int node = nodeBase + m0 + m;
        if (node < N_NODESC) {
            float4 z;
            z.x = acc[m][0] + b2v.x;
            z.y = acc[m][1] + b2v.y;
            z.z = acc[m][2] + b2v.z;
            z.w = acc[m][3] + b2v.w;
            *(float4*)(zout + (size_t)node * DIM + j4) = z;
            s1[0] += z.x; s2[0] += z.x * z.x;
            s1[1] += z.y; s2[1] += z.y * z.y;
            s1[2] += z.z; s2[2] += z.z * z.z;
            s1[3] += z.w; s2[3] += z.w * z.w;
        }
    }
    __syncthreads();                       // wch reads done; reuse as reduction scratch
    float* red = (float*)wch;
    *(float4*)&red[t * 8 + 0] = make_float4(s1[0], s1[1], s1[2], s1[3]);
    *(float4*)&red[t * 8 + 4] = make_float4(s2[0], s2[1], s2[2], s2[3]);
    __syncthreads();
    if (t < 32) {
        float4 S1 = make_float4(0.f, 0.f, 0.f, 0.f);
        float4 S2 = make_float4(0.f, 0.f, 0.f, 0.f);
#pragma unroll
        for (int g = 0; g < 8; ++g) {
            float4 u1 = *(float4*)&red[((g << 5) | t) * 8 + 0];
            float4 u2 = *(float4*)&red[((g << 5) | t) * 8 + 4];
            S1.x += u1.x; S1.y += u1.y; S1.z += u1.z; S1.w += u1.w;
            S2.x += u2.x; S2.y += u2.y; S2.z += u2.z; S2.w += u2.w;
        }
        *(float4*)(partials + (size_t)blockIdx.x * 256 + t * 4) = S1;
        *(float4*)(partials + (size_t)blockIdx.x * 256 + DIM + t * 4) = S2;
    }
}

// ---------------- stats reduce + BN finalize ----------------

__global__ __launch_bounds__(256) void reduce_stats(const float* __restrict__ partials,
                                                    float* __restrict__ stats) {
    int c = threadIdx.x;
    int r0 = blockIdx.x * RED_ROWS;
    int r1 = r0 + RED_ROWS;
    if (r1 > NBLK) r1 = NBLK;
    float s = 0.f;
    for (int r = r0; r < r1; ++r) s += partials[(size_t)r * 256 + c];
    atomicAdd(&stats[c], s);
}

__global__ void bn_finalize(const float* __restrict__ stats, const float* __restrict__ gamma,
                            const float* __restrict__ beta, float* __restrict__ ab) {
    int j = threadIdx.x;
    float s1 = stats[j], s2 = stats[DIM + j];
    const float invN = 1.0f / (float)N_NODESC;
    float mean = s1 * invN;
    float var = s2 * invN - mean * mean;
    float a = gamma[j] * rsqrtf(var + BN_EPSF);
    float b = beta[j] - mean * a;
    ab[j] = a;
    ab[DIM + j] = b;
}

// ---------------- global mean pool: one block per graph, applies last-layer BN+ReLU ----------------

__global__ __launch_bounds__(256) void pool_kernel(const float* __restrict__ z,
                                                   const int* __restrict__ gstart,
                                                   const float* __restrict__ ab,
                                                   float* __restrict__ outp) {
    __shared__ float sred[8][DIM];
    const int g = blockIdx.x;
    const int lane = threadIdx.x & 31;
    const int grp = threadIdx.x >> 5;
    const int c4 = lane << 2;
    const int ns = gstart[g], ne = gstart[g + 1];
    float4 a4 = *(const float4*)(ab + c4);
    float4 b4 = *(const float4*)(ab + DIM + c4);
    float4 acc = make_float4(0.f, 0.f, 0.f, 0.f);
    for (int m = ns + grp; m < ne; m += 8) {
        float4 v = *(const float4*)(z + (size_t)m * DIM + c4);
        v = bnrelu4(v, a4, b4);
        acc.x += v.x; acc.y += v.y; acc.z += v.z; acc.w += v.w;
    }
    *(float4*)&sred[grp][c4] = acc;
    __syncthreads();
    if (grp == 0) {
#pragma unroll
        for (int q = 1; q < 8; ++q) {
            float4 u = *(float4*)&sred[q][c4];
            acc.x += u.x; acc.y += u.y; acc.z += u.z; acc.w += u.w;
        }
        float inv = 1.0f / fmaxf((float)(ne - ns), 1.0f);
        float4 o = make_float4(acc.x * inv, acc.y * inv, acc.z * inv, acc.w * inv);
        *(float4*)(outp + (size_t)g * DIM + c4) = o;
    }
}

// ---------------- launcher ----------------

extern "C" void kernel_launch(void* const* d_in, const int* in_sizes, int n_in,
                              void* d_out, int out_size, void* d_ws, size_t ws_size,
                              hipStream_t stream) {
    const float* x     = (const float*)d_in[0];
    const int*   ei    = (const int*)d_in[1];
    const int*   batch = (const int*)d_in[2];
    const float* W1    = (const float*)d_in[3];
    const float* b1    = (const float*)d_in[4];
    const float* W2    = (const float*)d_in[5];
    const float* b2    = (const float*)d_in[6];
    const float* gamma = (const float*)d_in[7];
    const float* beta  = (const float*)d_in[8];
    float* out = (float*)d_out;

    char* ws = (char*)d_ws;
    size_t off = 0;
    auto alloc = [&](size_t bytes) -> void* {
        void* p = ws + off;
        off += (bytes + 255) & ~(size_t)255;
        return p;
    };
    int*   deg      = (int*)alloc((size_t)N_NODESC * 4);
    int*   offs     = (int*)alloc((size_t)(N_NODESC + 1) * 4);
    int*   cursor   = (int*)alloc((size_t)N_NODESC * 4);
    int*   csr      = (int*)alloc((size_t)N_EDGESC * 4);
    int*   gstart   = (int*)alloc((size_t)(N_GRAPHS + 1) * 4);
    float* stats    = (float*)alloc(256 * 4);
    float* ab       = (float*)alloc(256 * 4);
    float* partials = (float*)alloc((size_t)NBLK * 256 * 4);
    float* bufZ0    = (float*)alloc((size_t)N_NODESC * DIM * 4);
    float* bufZ1    = (float*)alloc((size_t)N_NODESC * DIM * 4);

    const int* srcp = ei;
    const int* dstp = ei + N_EDGESC;

    // CSR build
    hipMemsetAsync(deg, 0, (size_t)N_NODESC * 4, stream);
    hist_kernel<<<(N_EDGESC + 255) / 256, 256, 0, stream>>>(dstp, deg);
    scan_kernel<<<1, 1024, 0, stream>>>(deg, offs);
    hipMemcpyAsync(cursor, offs, (size_t)N_NODESC * 4, hipMemcpyDeviceToDevice, stream);
    fill_kernel<<<(N_EDGESC + 255) / 256, 256, 0, stream>>>(srcp, dstp, cursor, csr);

    // graph boundaries for the pool
    ginit_kernel<<<1, 256, 0, stream>>>(gstart);
    gbound_kernel<<<(N_NODESC + 255) / 256, 256, 0, stream>>>(batch, gstart);

    const float* hin = x;
    float* zbufs[2] = {bufZ0, bufZ1};
    for (int l = 0; l < N_LAYERS; ++l) {
        float* zout = zbufs[l & 1];
        const float* W1l = W1 + (size_t)l * DIM * DIM;
        const float* b1l = b1 + (size_t)l * DIM;
        const float* W2l = W2 + (size_t)l * DIM * DIM;
        const float* b2l = b2 + (size_t)l * DIM;
        if (l == 0)
            mlp_fused<0><<<NBLK, 256, 0, stream>>>(hin, nullptr, offs, csr, W1l, b1l, W2l, b2l,
                                                   zout, partials);
        else
            mlp_fused<1><<<NBLK, 256, 0, stream>>>(hin, ab, offs, csr, W1l, b1l, W2l, b2l,
                                                   zout, partials);
        hipMemsetAsync(stats, 0, 256 * 4, stream);
        reduce_stats<<<32, 256, 0, stream>>>(partials, stats);
        bn_finalize<<<1, DIM, 0, stream>>>(stats, gamma + (size_t)l * DIM, beta + (size_t)l * DIM, ab);
        hin = zout;
    }

    pool_kernel<<<N_GRAPHS, 256, 0, stream>>>(hin, gstart, ab, out);
}